// Round 6
// baseline (37.456 us; speedup 1.0000x reference)
//
#include <hip/hip_runtime.h>

// Bottom-up HTMM forward. One block per (tree-pair, generator); 16 groups of
// 16 lanes. Each group evaluates FOUR depth-5 subtrees (2 per tree) as a
// float4 register chain: 16x16 matvec via hand-fused v_fmac_f32_dpp
// (row_ror), reductions via v_add_f32_dpp. Top-31 nodes of both trees done
// as one float2 chain by group 0 (no barriers). Prologue softmaxes shared
// across the tree pair. log accumulated in log2, scaled once at the end.
#define G_   8
#define NT_  128
#define NPT_ 1023

typedef float f16v __attribute__((ext_vector_type(16)));
#define RCP(x) __builtin_amdgcn_rcpf(x)

// lane i receives v[(i - R) & 15] within its 16-lane row (row_ror)
template<int R>
__device__ __forceinline__ float rotr16(float v) {
  return __int_as_float(__builtin_amdgcn_update_dpp(
      0, __float_as_int(v), 0x120 | R, 0xF, 0xF, true));
}
// builtin-path reduces (compiler handles DPP hazards) — prologue only
__device__ __forceinline__ float grpsum16(float v) {
  v += rotr16<8>(v); v += rotr16<4>(v); v += rotr16<2>(v); v += rotr16<1>(v);
  return v;
}
__device__ __forceinline__ float grpmax16(float v) {
  v = fmaxf(v, rotr16<8>(v)); v = fmaxf(v, rotr16<4>(v));
  v = fmaxf(v, rotr16<2>(v)); v = fmaxf(v, rotr16<1>(v));
  return v;
}

// ---- 4 dots (top chain: L/R x 2 trees) with fused v_fmac_f32_dpp ----
#define FMAC4_R(R) \
  asm("v_fmac_f32_dpp %0, %4, %8 row_ror:" #R " row_mask:0xf bank_mask:0xf\n\t" \
      "v_fmac_f32_dpp %1, %5, %8 row_ror:" #R " row_mask:0xf bank_mask:0xf\n\t" \
      "v_fmac_f32_dpp %2, %6, %9 row_ror:" #R " row_mask:0xf bank_mask:0xf\n\t" \
      "v_fmac_f32_dpp %3, %7, %9 row_ror:" #R " row_mask:0xf bank_mask:0xf"     \
      : "+v"(aLx), "+v"(aLy), "+v"(aRx), "+v"(aRy)                              \
      : "v"(vLx), "v"(vLy), "v"(vRx), "v"(vRy), "v"(w0[R]), "v"(w1[R]))
#define FMAC4_FIRST(R) \
  asm("s_nop 1\n\t"                                                             \
      "v_fmac_f32_dpp %0, %4, %8 row_ror:" #R " row_mask:0xf bank_mask:0xf\n\t" \
      "v_fmac_f32_dpp %1, %5, %8 row_ror:" #R " row_mask:0xf bank_mask:0xf\n\t" \
      "v_fmac_f32_dpp %2, %6, %9 row_ror:" #R " row_mask:0xf bank_mask:0xf\n\t" \
      "v_fmac_f32_dpp %3, %7, %9 row_ror:" #R " row_mask:0xf bank_mask:0xf"     \
      : "+v"(aLx), "+v"(aLy), "+v"(aRx), "+v"(aRy)                              \
      : "v"(vLx), "v"(vLy), "v"(vRx), "v"(vRy), "v"(w0[R]), "v"(w1[R]))

__device__ __forceinline__ void dot4(float vLx, float vLy, float vRx, float vRy,
                                     const f16v& w0, const f16v& w1,
                                     float& oLx, float& oLy, float& oRx, float& oRy) {
  float aLx = vLx * w0[0];
  float aLy = vLy * w0[0];
  float aRx = vRx * w1[0];
  float aRy = vRy * w1[0];
  FMAC4_FIRST(1);
  FMAC4_R(2);  FMAC4_R(3);  FMAC4_R(4);  FMAC4_R(5);
  FMAC4_R(6);  FMAC4_R(7);  FMAC4_R(8);  FMAC4_R(9);
  FMAC4_R(10); FMAC4_R(11); FMAC4_R(12); FMAC4_R(13);
  FMAC4_R(14); FMAC4_R(15);
  oLx = aLx; oLy = aLy; oRx = aRx; oRy = aRy;
}

// ---- 8 dots (main chain: L/R x 4 subtree components), round-robin dist 8 ----
#define FMAC8_R(R) \
  asm("v_fmac_f32_dpp %0, %8, %16 row_ror:" #R " row_mask:0xf bank_mask:0xf\n\t"  \
      "v_fmac_f32_dpp %1, %9, %16 row_ror:" #R " row_mask:0xf bank_mask:0xf\n\t"  \
      "v_fmac_f32_dpp %2, %10, %16 row_ror:" #R " row_mask:0xf bank_mask:0xf\n\t" \
      "v_fmac_f32_dpp %3, %11, %16 row_ror:" #R " row_mask:0xf bank_mask:0xf\n\t" \
      "v_fmac_f32_dpp %4, %12, %17 row_ror:" #R " row_mask:0xf bank_mask:0xf\n\t" \
      "v_fmac_f32_dpp %5, %13, %17 row_ror:" #R " row_mask:0xf bank_mask:0xf\n\t" \
      "v_fmac_f32_dpp %6, %14, %17 row_ror:" #R " row_mask:0xf bank_mask:0xf\n\t" \
      "v_fmac_f32_dpp %7, %15, %17 row_ror:" #R " row_mask:0xf bank_mask:0xf"     \
      : "+v"(a0), "+v"(a1), "+v"(a2), "+v"(a3),                                   \
        "+v"(a4), "+v"(a5), "+v"(a6), "+v"(a7)                                    \
      : "v"(v0), "v"(v1), "v"(v2), "v"(v3),                                       \
        "v"(v4), "v"(v5), "v"(v6), "v"(v7), "v"(w0[R]), "v"(w1[R]))
#define FMAC8_FIRST(R) \
  asm("s_nop 1\n\t"                                                               \
      "v_fmac_f32_dpp %0, %8, %16 row_ror:" #R " row_mask:0xf bank_mask:0xf\n\t"  \
      "v_fmac_f32_dpp %1, %9, %16 row_ror:" #R " row_mask:0xf bank_mask:0xf\n\t"  \
      "v_fmac_f32_dpp %2, %10, %16 row_ror:" #R " row_mask:0xf bank_mask:0xf\n\t" \
      "v_fmac_f32_dpp %3, %11, %16 row_ror:" #R " row_mask:0xf bank_mask:0xf\n\t" \
      "v_fmac_f32_dpp %4, %12, %17 row_ror:" #R " row_mask:0xf bank_mask:0xf\n\t" \
      "v_fmac_f32_dpp %5, %13, %17 row_ror:" #R " row_mask:0xf bank_mask:0xf\n\t" \
      "v_fmac_f32_dpp %6, %14, %17 row_ror:" #R " row_mask:0xf bank_mask:0xf\n\t" \
      "v_fmac_f32_dpp %7, %15, %17 row_ror:" #R " row_mask:0xf bank_mask:0xf"     \
      : "+v"(a0), "+v"(a1), "+v"(a2), "+v"(a3),                                   \
        "+v"(a4), "+v"(a5), "+v"(a6), "+v"(a7)                                    \
      : "v"(v0), "v"(v1), "v"(v2), "v"(v3),                                       \
        "v"(v4), "v"(v5), "v"(v6), "v"(v7), "v"(w0[R]), "v"(w1[R]))

__device__ __forceinline__ void dot8(float v0, float v1, float v2, float v3,
                                     float v4, float v5, float v6, float v7,
                                     const f16v& w0, const f16v& w1,
                                     float& o0, float& o1, float& o2, float& o3,
                                     float& o4, float& o5, float& o6, float& o7) {
  float a0 = v0 * w0[0], a1 = v1 * w0[0], a2 = v2 * w0[0], a3 = v3 * w0[0];
  float a4 = v4 * w1[0], a5 = v5 * w1[0], a6 = v6 * w1[0], a7 = v7 * w1[0];
  FMAC8_FIRST(1);
  FMAC8_R(2);  FMAC8_R(3);  FMAC8_R(4);  FMAC8_R(5);
  FMAC8_R(6);  FMAC8_R(7);  FMAC8_R(8);  FMAC8_R(9);
  FMAC8_R(10); FMAC8_R(11); FMAC8_R(12); FMAC8_R(13);
  FMAC8_R(14); FMAC8_R(15);
  o0 = a0; o1 = a1; o2 = a2; o3 = a3;
  o4 = a4; o5 = a5; o6 = a6; o7 = a7;
}

// dual 16-lane sum with explicit hazard nops (adjacent-dep chains)
__device__ __forceinline__ void grpsum2(float rx, float ry, float& nux, float& nuy) {
  asm("s_nop 1\n\t"
      "v_add_f32_dpp %0, %2, %2 row_ror:8 row_mask:0xf bank_mask:0xf\n\t"
      "v_add_f32_dpp %1, %3, %3 row_ror:8 row_mask:0xf bank_mask:0xf\n\t"
      "s_nop 0\n\t"
      "v_add_f32_dpp %0, %0, %0 row_ror:4 row_mask:0xf bank_mask:0xf\n\t"
      "v_add_f32_dpp %1, %1, %1 row_ror:4 row_mask:0xf bank_mask:0xf\n\t"
      "s_nop 0\n\t"
      "v_add_f32_dpp %0, %0, %0 row_ror:2 row_mask:0xf bank_mask:0xf\n\t"
      "v_add_f32_dpp %1, %1, %1 row_ror:2 row_mask:0xf bank_mask:0xf\n\t"
      "s_nop 0\n\t"
      "v_add_f32_dpp %0, %0, %0 row_ror:1 row_mask:0xf bank_mask:0xf\n\t"
      "v_add_f32_dpp %1, %1, %1 row_ror:1 row_mask:0xf bank_mask:0xf"
      : "=&v"(nux), "=&v"(nuy)
      : "v"(rx), "v"(ry));
}

// quad 16-lane sum: 4 interleaved DPP chains, round-robin distance 4
__device__ __forceinline__ void grpsum4(float r0, float r1, float r2, float r3,
                                        float& n0, float& n1, float& n2, float& n3) {
  asm("s_nop 1\n\t"
      "v_add_f32_dpp %0, %4, %4 row_ror:8 row_mask:0xf bank_mask:0xf\n\t"
      "v_add_f32_dpp %1, %5, %5 row_ror:8 row_mask:0xf bank_mask:0xf\n\t"
      "v_add_f32_dpp %2, %6, %6 row_ror:8 row_mask:0xf bank_mask:0xf\n\t"
      "v_add_f32_dpp %3, %7, %7 row_ror:8 row_mask:0xf bank_mask:0xf\n\t"
      "v_add_f32_dpp %0, %0, %0 row_ror:4 row_mask:0xf bank_mask:0xf\n\t"
      "v_add_f32_dpp %1, %1, %1 row_ror:4 row_mask:0xf bank_mask:0xf\n\t"
      "v_add_f32_dpp %2, %2, %2 row_ror:4 row_mask:0xf bank_mask:0xf\n\t"
      "v_add_f32_dpp %3, %3, %3 row_ror:4 row_mask:0xf bank_mask:0xf\n\t"
      "v_add_f32_dpp %0, %0, %0 row_ror:2 row_mask:0xf bank_mask:0xf\n\t"
      "v_add_f32_dpp %1, %1, %1 row_ror:2 row_mask:0xf bank_mask:0xf\n\t"
      "v_add_f32_dpp %2, %2, %2 row_ror:2 row_mask:0xf bank_mask:0xf\n\t"
      "v_add_f32_dpp %3, %3, %3 row_ror:2 row_mask:0xf bank_mask:0xf\n\t"
      "v_add_f32_dpp %0, %0, %0 row_ror:1 row_mask:0xf bank_mask:0xf\n\t"
      "v_add_f32_dpp %1, %1, %1 row_ror:1 row_mask:0xf bank_mask:0xf\n\t"
      "v_add_f32_dpp %2, %2, %2 row_ror:1 row_mask:0xf bank_mask:0xf\n\t"
      "v_add_f32_dpp %3, %3, %3 row_ror:1 row_mask:0xf bank_mask:0xf"
      : "=&v"(n0), "=&v"(n1), "=&v"(n2), "=&v"(n3)
      : "v"(r0), "v"(r1), "v"(r2), "v"(r3));
}

// Post-order evaluation of four depth-5 subtrees at once (components:
// 0,1 = tree0 subtrees s, s+16; 2,3 = tree1 subtrees s, s+16).
template<int DELTA, int J>
__device__ __forceinline__ void evalN4(const float* __restrict__ sBa,
                                       const f16v& w0, const f16v& w1,
                                       const f16v& lf0, const f16v& lf1,
                                       const f16v& lf2, const f16v& lf3,
                                       int intp0, int intp1,
                                       float4& ll, float4& raw, float4& rcpv) {
  // prefetch this node's B-gathers before descending (hides LDS latency)
  int idx = (1 << DELTA) - 1 + J;
  int xp0 = __shfl(intp0, idx, 16);
  int xp1 = __shfl(intp1, idx, 16);
  float bv0 = sBa[xp0 & 0xFFFF];
  float bv1 = sBa[((unsigned)xp0) >> 16];
  float bv2 = sBa[xp1 & 0xFFFF];
  float bv3 = sBa[((unsigned)xp1) >> 16];
  float4 rawL, rcpL, rawR, rcpR;
  if constexpr (DELTA == 3) {
    rawL.x = lf0[2 * J];     rawL.y = lf1[2 * J];
    rawL.z = lf2[2 * J];     rawL.w = lf3[2 * J];
    rawR.x = lf0[2 * J + 1]; rawR.y = lf1[2 * J + 1];
    rawR.z = lf2[2 * J + 1]; rawR.w = lf3[2 * J + 1];
    float n0, n1, n2, n3, m0, m1, m2, m3;
    grpsum4(rawL.x, rawL.y, rawL.z, rawL.w, n0, n1, n2, n3);
    grpsum4(rawR.x, rawR.y, rawR.z, rawR.w, m0, m1, m2, m3);
    ll.x += __log2f(n0) + __log2f(m0);
    ll.y += __log2f(n1) + __log2f(m1);
    ll.z += __log2f(n2) + __log2f(m2);
    ll.w += __log2f(n3) + __log2f(m3);
    rcpL.x = RCP(n0); rcpL.y = RCP(n1); rcpL.z = RCP(n2); rcpL.w = RCP(n3);
    rcpR.x = RCP(m0); rcpR.y = RCP(m1); rcpR.z = RCP(m2); rcpR.w = RCP(m3);
  } else {
    evalN4<DELTA + 1, 2 * J>(sBa, w0, w1, lf0, lf1, lf2, lf3, intp0, intp1,
                             ll, rawL, rcpL);
    evalN4<DELTA + 1, 2 * J + 1>(sBa, w0, w1, lf0, lf1, lf2, lf3, intp0, intp1,
                                 ll, rawR, rcpR);
  }
  float d0, d1, d2, d3, d4, d5, d6, d7;
  dot8(rawL.x, rawL.y, rawL.z, rawL.w, rawR.x, rawR.y, rawR.z, rawR.w,
       w0, w1, d0, d1, d2, d3, d4, d5, d6, d7);
  float t0 = fmaf(d0, rcpL.x, d4 * rcpR.x);
  float t1 = fmaf(d1, rcpL.y, d5 * rcpR.y);
  float t2 = fmaf(d2, rcpL.z, d6 * rcpR.z);
  float t3 = fmaf(d3, rcpL.w, d7 * rcpR.w);
  raw.x = t0 * bv0; raw.y = t1 * bv1; raw.z = t2 * bv2; raw.w = t3 * bv3;
  float n0, n1, n2, n3;
  grpsum4(raw.x, raw.y, raw.z, raw.w, n0, n1, n2, n3);
  ll.x += __log2f(n0); ll.y += __log2f(n1);
  ll.z += __log2f(n2); ll.w += __log2f(n3);
  rcpv.x = RCP(n0); rcpv.y = RCP(n1); rcpv.z = RCP(n2); rcpv.w = RCP(n3);
}

template<int I>
__device__ __forceinline__ float pick32(const f16v& lo, const f16v& hi) {
  if constexpr (I < 16) return lo[I];
  else return hi[I - 16];
}

// Top-31 nodes of both trees as one float2 chain (x = tree0, y = tree1).
// LVL 0..4; at LVL==4 consume two normalized subtree-root beliefs (rcp=1).
template<int LVL, int J>
__device__ __forceinline__ void evalTop(const float* __restrict__ sBa,
                                        const f16v& r0a, const f16v& r0b,
                                        const f16v& r1a, const f16v& r1b,
                                        const f16v& w0, const f16v& w1,
                                        int topp0, int topp1,
                                        float2& ll, float2& raw, float2& rcpv) {
  float bv0, bv1;
  float2 rawL, rcpL, rawR, rcpR;
  if constexpr (LVL == 4) {
    int xp0 = __shfl(topp0, J, 16);            // high half: node 15+J
    int xp1 = __shfl(topp1, J, 16);
    bv0 = sBa[((unsigned)xp0) >> 16];
    bv1 = sBa[((unsigned)xp1) >> 16];
    rawL.x = pick32<2 * J>(r0a, r0b);     rawL.y = pick32<2 * J>(r1a, r1b);
    rawR.x = pick32<2 * J + 1>(r0a, r0b); rawR.y = pick32<2 * J + 1>(r1a, r1b);
    rcpL.x = 1.f; rcpL.y = 1.f; rcpR.x = 1.f; rcpR.y = 1.f;
  } else {
    int idx = (1 << LVL) - 1 + J;              // low half: node idx (0..14)
    int xp0 = __shfl(topp0, idx, 16);
    int xp1 = __shfl(topp1, idx, 16);
    bv0 = sBa[xp0 & 0xFFFF];
    bv1 = sBa[xp1 & 0xFFFF];
    evalTop<LVL + 1, 2 * J>(sBa, r0a, r0b, r1a, r1b, w0, w1, topp0, topp1,
                            ll, rawL, rcpL);
    evalTop<LVL + 1, 2 * J + 1>(sBa, r0a, r0b, r1a, r1b, w0, w1, topp0, topp1,
                                ll, rawR, rcpR);
  }
  float dL0, dL1, dR0, dR1;
  dot4(rawL.x, rawL.y, rawR.x, rawR.y, w0, w1, dL0, dL1, dR0, dR1);
  float t0 = fmaf(dL0, rcpL.x, dR0 * rcpR.x);
  float t1 = fmaf(dL1, rcpL.y, dR1 * rcpR.y);
  raw.x = t0 * bv0; raw.y = t1 * bv1;
  float n0, n1;
  grpsum2(raw.x, raw.y, n0, n1);
  ll.x += __log2f(n0); ll.y += __log2f(n1);
  rcpv.x = RCP(n0); rcpv.y = RCP(n1);
}

__global__ __launch_bounds__(256, 2) void htmm_fwd_kernel(
    const float* __restrict__ lA,   // (16,16,2,8)
    const float* __restrict__ lB,   // (16,256,8)
    const float* __restrict__ lPi,  // (16,2,8)
    const float* __restrict__ lSP,  // (2,8)
    const int*   __restrict__ x,    // (128*1023,)
    float*       __restrict__ out)  // (128,8)
{
  __shared__ float sB[256 * 17];    // normalized B, [m][c], stride 17
  __shared__ float sA[2 * 16 * 16]; // normalized A, [l][b][a]
  __shared__ float sPi[32];         // [l][c]
  __shared__ float roots0[32 * 17]; // tree0 subtree-root beliefs
  __shared__ float roots1[32 * 17]; // tree1 subtree-root beliefs
  __shared__ float red[8];

  const int tid = threadIdx.x;
  const int bid = blockIdx.x;       // tree_pair*8 + g
  const int tp  = bid >> 3;
  const int g   = bid & 7;
  const int a   = tid & 15;
  const int grp = tid >> 4;
  const long b0 = (long)(2 * tp) * NPT_;
  const long b1 = b0 + NPT_;

  // ---- SP softmax ----
  float s0 = lSP[g], s1 = lSP[G_ + g];
  float sm = fmaxf(s0, s1);
  float e0 = __expf(s0 - sm), e1 = __expf(s1 - sm);
  float inv = RCP(e0 + e1);
  const float SP0 = e0 * inv, SP1 = e1 * inv;

  // ---- A softmax over axis 0 (lanes = a), column b = grp ----
  #pragma unroll
  for (int l = 0; l < 2; ++l) {
    float v = lA[a * 256 + grp * 16 + l * 8 + g];
    float m = grpmax16(v);
    float e = __expf(v - m);
    float s = grpsum16(e);
    sA[(l * 16 + grp) * 16 + a] = e * RCP(s);
  }
  // ---- Pi softmax over axis 0 ----
  if (grp < 2) {
    float v = lPi[a * 16 + grp * 8 + g];
    float m = grpmax16(v);
    float e = __expf(v - m);
    float s = grpsum16(e);
    sPi[grp * 16 + a] = e * RCP(s);
  }
  // ---- B softmax over axis 1 (M): row c = grp, lane a covers m = a+16k ----
  {
    const int c = grp;
    float vv[16];
    float mx = -1e30f;
    #pragma unroll
    for (int k = 0; k < 16; ++k) {
      vv[k] = lB[c * (256 * G_) + (a + 16 * k) * G_ + g];
      mx = fmaxf(mx, vv[k]);
    }
    mx = grpmax16(mx);
    float ssum = 0.f;
    #pragma unroll
    for (int k = 0; k < 16; ++k) { vv[k] = __expf(vv[k] - mx); ssum += vv[k]; }
    ssum = grpsum16(ssum);
    float is = RCP(ssum);
    #pragma unroll
    for (int k = 0; k < 16; ++k) sB[(a + 16 * k) * 17 + c] = vv[k] * is;
  }

  // ---- observation indices, pre-scaled by 17 and packed (x<256 => <16b) ----
  int leafp0 = (x[b0 + 511 + 16 * grp + a] * 17) |
               ((x[b0 + 511 + 16 * (grp + 16) + a] * 17) << 16);
  int leafp1 = (x[b1 + 511 + 16 * grp + a] * 17) |
               ((x[b1 + 511 + 16 * (grp + 16) + a] * 17) << 16);
  int dpl = 31 - __clz(a + 1);
  int intp0 = ((a < 15) ? x[b0 + ((31 + grp) << dpl) + a] * 17 : 0) |
              (((a < 15) ? x[b0 + ((31 + grp + 16) << dpl) + a] * 17 : 0) << 16);
  int intp1 = ((a < 15) ? x[b1 + ((31 + grp) << dpl) + a] * 17 : 0) |
              (((a < 15) ? x[b1 + ((31 + grp + 16) << dpl) + a] * 17 : 0) << 16);
  // top-31 packs: low16 = x[node a] (a<15), high16 = x[node 15+a]
  int topp0 = ((a < 15) ? x[b0 + a] * 17 : 0) | ((x[b0 + 15 + a] * 17) << 16);
  int topp1 = ((a < 15) ? x[b1 + a] * 17 : 0) | ((x[b1 + 15 + a] * 17) << 16);

  __syncthreads();

  // ---- per-lane rotated weight vectors: w[r] = A[a][(a-r)&15][l] * SP[l] ----
  f16v w0, w1;
  #pragma unroll
  for (int r = 0; r < 16; ++r) {
    int b = (a - r) & 15;
    w0[r] = sA[b * 16 + a] * SP0;
    w1[r] = sA[(16 + b) * 16 + a] * SP1;
  }
  const float pi0 = sPi[a], pi1 = sPi[16 + a];
  const float* sBa = sB + a;

  // ---- hoist all 64 leaf gathers: pipelined bpermute+LDS reads up front ----
  f16v lf0, lf1, lf2, lf3;
  #pragma unroll
  for (int j = 0; j < 16; ++j) {
    int xp0 = __shfl(leafp0, j, 16);
    int xp1 = __shfl(leafp1, j, 16);
    float pi = (j & 1) ? pi1 : pi0;
    lf0[j] = pi * sBa[xp0 & 0xFFFF];
    lf1[j] = pi * sBa[((unsigned)xp0) >> 16];
    lf2[j] = pi * sBa[xp1 & 0xFFFF];
    lf3[j] = pi * sBa[((unsigned)xp1) >> 16];
  }

  float4 ll = {0.f, 0.f, 0.f, 0.f};
  float4 rraw, rrcp;
  evalN4<0, 0>(sBa, w0, w1, lf0, lf1, lf2, lf3, intp0, intp1, ll, rraw, rrcp);
  roots0[grp * 17 + a]        = rraw.x * rrcp.x;
  roots0[(grp + 16) * 17 + a] = rraw.y * rrcp.y;
  roots1[grp * 17 + a]        = rraw.z * rrcp.z;
  roots1[(grp + 16) * 17 + a] = rraw.w * rrcp.w;
  __syncthreads();

  // ---- top 31 nodes of both trees: one float2 chain by group 0 ----
  float2 llt = {0.f, 0.f};
  if (tid < 16) {
    f16v r0a, r0b, r1a, r1b;
    #pragma unroll
    for (int j = 0; j < 16; ++j) {
      r0a[j] = roots0[j * 17 + a];
      r0b[j] = roots0[(16 + j) * 17 + a];
      r1a[j] = roots1[j * 17 + a];
      r1b[j] = roots1[(16 + j) * 17 + a];
    }
    float2 traw, trcp;
    evalTop<0, 0>(sBa, r0a, r0b, r1a, r1b, w0, w1, topp0, topp1,
                  llt, traw, trcp);
  }

  // ---- block reduce per tree; scale: x16 lane duplication, log2 -> ln ----
  float v0 = ll.x + ll.y + llt.x;
  float v1 = ll.z + ll.w + llt.y;
  #pragma unroll
  for (int off = 32; off > 0; off >>= 1) {
    v0 += __shfl_down(v0, off, 64);
    v1 += __shfl_down(v1, off, 64);
  }
  if ((tid & 63) == 0) {
    red[(tid >> 6) * 2]     = v0;
    red[(tid >> 6) * 2 + 1] = v1;
  }
  __syncthreads();
  if (tid == 0) {
    const float sc = 0.6931471805599453f / 16.f;
    out[(2 * tp) * G_ + g]     = (red[0] + red[2] + red[4] + red[6]) * sc;
    out[(2 * tp + 1) * G_ + g] = (red[1] + red[3] + red[5] + red[7]) * sc;
  }
}

extern "C" void kernel_launch(void* const* d_in, const int* in_sizes, int n_in,
                              void* d_out, int out_size, void* d_ws, size_t ws_size,
                              hipStream_t stream) {
  const float* lA  = (const float*)d_in[0];
  const float* lB  = (const float*)d_in[1];
  const float* lPi = (const float*)d_in[2];
  const float* lSP = (const float*)d_in[3];
  const int*   x   = (const int*)d_in[4];
  float* out = (float*)d_out;
  htmm_fwd_kernel<<<dim3((NT_ / 2) * G_), dim3(256), 0, stream>>>(
      lA, lB, lPi, lSP, x, out);
}

// Round 7
// 26.621 us; speedup vs baseline: 1.4070x; 1.4070x over previous
//
#include <hip/hip_runtime.h>

// Bottom-up HTMM forward. One block per (tree, generator); 16 groups of 16
// lanes. Each group evaluates its two depth-5 subtrees as float2 register
// chains; 16x16 matvec with hand-fused v_fmac_f32_dpp (row_ror); 16-lane
// reductions with v_add_f32_dpp. Leaf gathers hoisted+pipelined at chain
// start; all global x loads hoisted above the softmax prologue; node nus
// logged pairwise (log2(nuL*nuR) at the parent). Scaled once at the end.
#define G_   8
#define NT_  128
#define NPT_ 1023

typedef float f16v __attribute__((ext_vector_type(16)));
#define RCP(x) __builtin_amdgcn_rcpf(x)

// lane i receives v[(i - R) & 15] within its 16-lane row (row_ror)
template<int R>
__device__ __forceinline__ float rotr16(float v) {
  return __int_as_float(__builtin_amdgcn_update_dpp(
      0, __float_as_int(v), 0x120 | R, 0xF, 0xF, true));
}
// builtin-path reduces (compiler handles DPP hazards) — prologue/top only
__device__ __forceinline__ float grpsum16(float v) {
  v += rotr16<8>(v); v += rotr16<4>(v); v += rotr16<2>(v); v += rotr16<1>(v);
  return v;
}
__device__ __forceinline__ float grpmax16(float v) {
  v = fmaxf(v, rotr16<8>(v)); v = fmaxf(v, rotr16<4>(v));
  v = fmaxf(v, rotr16<2>(v)); v = fmaxf(v, rotr16<1>(v));
  return v;
}

// ---- hot path: 4 dots (L/R children x float2) with fused v_fmac_f32_dpp.
// Round-robin over 4 accumulators: self-dep distance 4 >= FMA latency; DPP
// source operands written well before (s_nop 1 guards block entry).
#define FMAC4_R(R) \
  asm("v_fmac_f32_dpp %0, %4, %8 row_ror:" #R " row_mask:0xf bank_mask:0xf\n\t" \
      "v_fmac_f32_dpp %1, %5, %8 row_ror:" #R " row_mask:0xf bank_mask:0xf\n\t" \
      "v_fmac_f32_dpp %2, %6, %9 row_ror:" #R " row_mask:0xf bank_mask:0xf\n\t" \
      "v_fmac_f32_dpp %3, %7, %9 row_ror:" #R " row_mask:0xf bank_mask:0xf"     \
      : "+v"(aLx), "+v"(aLy), "+v"(aRx), "+v"(aRy)                              \
      : "v"(vLx), "v"(vLy), "v"(vRx), "v"(vRy), "v"(w0[R]), "v"(w1[R]))
#define FMAC4_FIRST(R) \
  asm("s_nop 1\n\t"                                                             \
      "v_fmac_f32_dpp %0, %4, %8 row_ror:" #R " row_mask:0xf bank_mask:0xf\n\t" \
      "v_fmac_f32_dpp %1, %5, %8 row_ror:" #R " row_mask:0xf bank_mask:0xf\n\t" \
      "v_fmac_f32_dpp %2, %6, %9 row_ror:" #R " row_mask:0xf bank_mask:0xf\n\t" \
      "v_fmac_f32_dpp %3, %7, %9 row_ror:" #R " row_mask:0xf bank_mask:0xf"     \
      : "+v"(aLx), "+v"(aLy), "+v"(aRx), "+v"(aRy)                              \
      : "v"(vLx), "v"(vLy), "v"(vRx), "v"(vRy), "v"(w0[R]), "v"(w1[R]))

__device__ __forceinline__ void dot4(float vLx, float vLy, float vRx, float vRy,
                                     const f16v& w0, const f16v& w1,
                                     float& oLx, float& oLy, float& oRx, float& oRy) {
  float aLx = vLx * w0[0];
  float aLy = vLy * w0[0];
  float aRx = vRx * w1[0];
  float aRy = vRy * w1[0];
  FMAC4_FIRST(1);
  FMAC4_R(2);  FMAC4_R(3);  FMAC4_R(4);  FMAC4_R(5);
  FMAC4_R(6);  FMAC4_R(7);  FMAC4_R(8);  FMAC4_R(9);
  FMAC4_R(10); FMAC4_R(11); FMAC4_R(12); FMAC4_R(13);
  FMAC4_R(14); FMAC4_R(15);
  oLx = aLx; oLy = aLy; oRx = aRx; oRy = aRy;
}

// ---- top phase: 2 dots fused (self-dep distance 2 instrs = 4 cy = FMA lat)
#define FMAC2_R(R) \
  asm("v_fmac_f32_dpp %0, %2, %4 row_ror:" #R " row_mask:0xf bank_mask:0xf\n\t" \
      "v_fmac_f32_dpp %1, %3, %5 row_ror:" #R " row_mask:0xf bank_mask:0xf"     \
      : "+v"(aL), "+v"(aR)                                                      \
      : "v"(vL), "v"(vR), "v"(w0[R]), "v"(w1[R]))
#define FMAC2_FIRST(R) \
  asm("s_nop 1\n\t"                                                             \
      "v_fmac_f32_dpp %0, %2, %4 row_ror:" #R " row_mask:0xf bank_mask:0xf\n\t" \
      "v_fmac_f32_dpp %1, %3, %5 row_ror:" #R " row_mask:0xf bank_mask:0xf"     \
      : "+v"(aL), "+v"(aR)                                                      \
      : "v"(vL), "v"(vR), "v"(w0[R]), "v"(w1[R]))

__device__ __forceinline__ void dot2f(float vL, float vR,
                                      const f16v& w0, const f16v& w1,
                                      float& oL, float& oR) {
  float aL = vL * w0[0];
  float aR = vR * w1[0];
  FMAC2_FIRST(1);
  FMAC2_R(2);  FMAC2_R(3);  FMAC2_R(4);  FMAC2_R(5);
  FMAC2_R(6);  FMAC2_R(7);  FMAC2_R(8);  FMAC2_R(9);
  FMAC2_R(10); FMAC2_R(11); FMAC2_R(12); FMAC2_R(13);
  FMAC2_R(14); FMAC2_R(15);
  oL = aL; oR = aR;
}

// dual 16-lane sum via v_add_f32_dpp; s_nops cover the same-reg
// VALU-write -> DPP-read hazard the compiler can't see.
__device__ __forceinline__ void grpsum2(float rx, float ry, float& nux, float& nuy) {
  asm("s_nop 1\n\t"
      "v_add_f32_dpp %0, %2, %2 row_ror:8 row_mask:0xf bank_mask:0xf\n\t"
      "v_add_f32_dpp %1, %3, %3 row_ror:8 row_mask:0xf bank_mask:0xf\n\t"
      "s_nop 0\n\t"
      "v_add_f32_dpp %0, %0, %0 row_ror:4 row_mask:0xf bank_mask:0xf\n\t"
      "v_add_f32_dpp %1, %1, %1 row_ror:4 row_mask:0xf bank_mask:0xf\n\t"
      "s_nop 0\n\t"
      "v_add_f32_dpp %0, %0, %0 row_ror:2 row_mask:0xf bank_mask:0xf\n\t"
      "v_add_f32_dpp %1, %1, %1 row_ror:2 row_mask:0xf bank_mask:0xf\n\t"
      "s_nop 0\n\t"
      "v_add_f32_dpp %0, %0, %0 row_ror:1 row_mask:0xf bank_mask:0xf\n\t"
      "v_add_f32_dpp %1, %1, %1 row_ror:1 row_mask:0xf bank_mask:0xf"
      : "=&v"(nux), "=&v"(nuy)
      : "v"(rx), "v"(ry));
}

// quad 16-lane sum: 4 interleaved DPP chains, round-robin distance 4 -> no
// nops needed (inputs are long-lived leaf registers).
__device__ __forceinline__ void grpsum4(float r0, float r1, float r2, float r3,
                                        float& n0, float& n1, float& n2, float& n3) {
  asm("v_add_f32_dpp %0, %4, %4 row_ror:8 row_mask:0xf bank_mask:0xf\n\t"
      "v_add_f32_dpp %1, %5, %5 row_ror:8 row_mask:0xf bank_mask:0xf\n\t"
      "v_add_f32_dpp %2, %6, %6 row_ror:8 row_mask:0xf bank_mask:0xf\n\t"
      "v_add_f32_dpp %3, %7, %7 row_ror:8 row_mask:0xf bank_mask:0xf\n\t"
      "v_add_f32_dpp %0, %0, %0 row_ror:4 row_mask:0xf bank_mask:0xf\n\t"
      "v_add_f32_dpp %1, %1, %1 row_ror:4 row_mask:0xf bank_mask:0xf\n\t"
      "v_add_f32_dpp %2, %2, %2 row_ror:4 row_mask:0xf bank_mask:0xf\n\t"
      "v_add_f32_dpp %3, %3, %3 row_ror:4 row_mask:0xf bank_mask:0xf\n\t"
      "v_add_f32_dpp %0, %0, %0 row_ror:2 row_mask:0xf bank_mask:0xf\n\t"
      "v_add_f32_dpp %1, %1, %1 row_ror:2 row_mask:0xf bank_mask:0xf\n\t"
      "v_add_f32_dpp %2, %2, %2 row_ror:2 row_mask:0xf bank_mask:0xf\n\t"
      "v_add_f32_dpp %3, %3, %3 row_ror:2 row_mask:0xf bank_mask:0xf\n\t"
      "v_add_f32_dpp %0, %0, %0 row_ror:1 row_mask:0xf bank_mask:0xf\n\t"
      "v_add_f32_dpp %1, %1, %1 row_ror:1 row_mask:0xf bank_mask:0xf\n\t"
      "v_add_f32_dpp %2, %2, %2 row_ror:1 row_mask:0xf bank_mask:0xf\n\t"
      "v_add_f32_dpp %3, %3, %3 row_ror:1 row_mask:0xf bank_mask:0xf"
      : "=&v"(n0), "=&v"(n1), "=&v"(n2), "=&v"(n3)
      : "v"(r0), "v"(r1), "v"(r2), "v"(r3));
}

// Post-order evaluation of two depth-5 subtrees at once (float2 lanes .x/.y).
// DELTA 0..3; leaves (DELTA 4) are pre-gathered registers consumed at DELTA 3.
// Each node RETURNS its nu (unlogged); the parent logs log2(nuL*nuR) —
// halves the transcendental count. Root nu logged by the caller.
template<int DELTA, int J>
__device__ __forceinline__ void evalN(const float* __restrict__ sBa,
                                      const f16v& w0, const f16v& w1,
                                      const f16v& lfx, const f16v& lfy,
                                      int intp,
                                      float2& ll, float2& raw, float2& rcpv,
                                      float2& nuOut) {
  // prefetch this node's B-gather before descending (hides LDS latency)
  int xp = __shfl(intp, (1 << DELTA) - 1 + J, 16);
  float bvA = sBa[xp & 0xFFFF];
  float bvB = sBa[((unsigned)xp) >> 16];
  float2 rawL, rcpL, rawR, rcpR;
  if constexpr (DELTA == 3) {
    // leaves 2J, 2J+1 from hoisted registers; one 4-wide reduce, paired logs
    float rLx = lfx[2 * J],     rLy = lfy[2 * J];
    float rRx = lfx[2 * J + 1], rRy = lfy[2 * J + 1];
    float nLx, nLy, nRx, nRy;
    grpsum4(rLx, rLy, rRx, rRy, nLx, nLy, nRx, nRy);
    ll.x += __log2f(nLx * nRx);
    ll.y += __log2f(nLy * nRy);
    rawL.x = rLx; rawL.y = rLy; rawR.x = rRx; rawR.y = rRy;
    rcpL.x = RCP(nLx); rcpL.y = RCP(nLy);
    rcpR.x = RCP(nRx); rcpR.y = RCP(nRy);
  } else {
    float2 nuL, nuR;
    evalN<DELTA + 1, 2 * J>(sBa, w0, w1, lfx, lfy, intp, ll, rawL, rcpL, nuL);
    evalN<DELTA + 1, 2 * J + 1>(sBa, w0, w1, lfx, lfy, intp, ll, rawR, rcpR, nuR);
    ll.x += __log2f(nuL.x * nuR.x);
    ll.y += __log2f(nuL.y * nuR.y);
  }
  float dLx, dLy, dRx, dRy;
  dot4(rawL.x, rawL.y, rawR.x, rawR.y, w0, w1, dLx, dLy, dRx, dRy);
  float tx = fmaf(dLx, rcpL.x, dRx * rcpR.x);
  float ty = fmaf(dLy, rcpL.y, dRy * rcpR.y);
  raw.x = tx * bvA;
  raw.y = ty * bvB;
  float nux, nuy;
  grpsum2(raw.x, raw.y, nux, nuy);
  nuOut.x = nux; nuOut.y = nuy;
  rcpv.x = RCP(nux);
  rcpv.y = RCP(nuy);
}

__device__ __forceinline__ void topStep(const float* __restrict__ child,
                                        float* parent, int U, int lvl,
                                        const float* __restrict__ sB,
                                        const f16v& w0, const f16v& w1,
                                        int a, int grp, int topx, float& ll) {
  int j = (grp < U) ? grp : 0;            // clamp: keep full-wave EXEC for DPP
  int node = (1 << lvl) - 1 + j;
  int xi = __shfl(topx, node, 64);
  float bval = sB[xi * 17 + a];
  float vL = child[(2 * j) * 17 + a];
  float vR = child[(2 * j + 1) * 17 + a];
  float dL, dR;
  dot2f(vL, vR, w0, w1, dL, dR);
  float bu = (dL + dR) * bval;
  float nu = grpsum16(bu);
  if (grp < U) {
    ll += __log2f(nu);
    if (parent) parent[grp * 17 + a] = bu * RCP(nu);
  }
  __syncthreads();
}

__global__ __launch_bounds__(256, 4) void htmm_fwd_kernel(
    const float* __restrict__ lA,   // (16,16,2,8)
    const float* __restrict__ lB,   // (16,256,8)
    const float* __restrict__ lPi,  // (16,2,8)
    const float* __restrict__ lSP,  // (2,8)
    const int*   __restrict__ x,    // (128*1023,)
    float*       __restrict__ out)  // (128,8)
{
  __shared__ float sB[256 * 17];    // normalized B, [m][c], stride 17
  __shared__ float sA[2 * 16 * 16]; // normalized A, [l][b][a]
  __shared__ float sPi[32];         // [l][c]
  __shared__ float roots[32 * 17];  // subtree-root beliefs (normalized)
  __shared__ float topA[16 * 17];
  __shared__ float topB[8 * 17];
  __shared__ float red[4];

  const int tid = threadIdx.x;
  const int bid = blockIdx.x;       // tree*8 + g
  const int T   = bid >> 3;
  const int g   = bid & 7;
  const int a   = tid & 15;
  const int grp = tid >> 4;
  const long base = (long)T * NPT_;

  // ---- ALL global x loads first: latency hides under the softmax prologue --
  int lxA = x[base + 511 + 16 * grp + a] * 17;
  int lxB = x[base + 511 + 16 * (grp + 16) + a] * 17;
  int leafp = lxA | (lxB << 16);
  int dpl = 31 - __clz(a + 1);
  int iA = (a < 15) ? x[base + ((31 + grp) << dpl) + a] * 17 : 0;
  int iB = (a < 15) ? x[base + ((31 + grp + 16) << dpl) + a] * 17 : 0;
  int intp = iA | (iB << 16);
  int tl = tid & 63;
  int topx = x[base + (tl < 31 ? tl : 0)];           // x[0..30] in wave lanes

  // ---- SP softmax ----
  float s0 = lSP[g], s1 = lSP[G_ + g];
  float sm = fmaxf(s0, s1);
  float e0 = __expf(s0 - sm), e1 = __expf(s1 - sm);
  float inv = RCP(e0 + e1);
  const float SP0 = e0 * inv, SP1 = e1 * inv;

  // ---- A softmax over axis 0 (lanes = a), column b = grp ----
  #pragma unroll
  for (int l = 0; l < 2; ++l) {
    float v = lA[a * 256 + grp * 16 + l * 8 + g];
    float m = grpmax16(v);
    float e = __expf(v - m);
    float s = grpsum16(e);
    sA[(l * 16 + grp) * 16 + a] = e * RCP(s);
  }
  // ---- Pi softmax over axis 0 ----
  if (grp < 2) {
    float v = lPi[a * 16 + grp * 8 + g];
    float m = grpmax16(v);
    float e = __expf(v - m);
    float s = grpsum16(e);
    sPi[grp * 16 + a] = e * RCP(s);
  }
  // ---- B softmax over axis 1 (M): row c = grp, lane a covers m = a+16k ----
  {
    const int c = grp;
    float vv[16];
    float mx = -1e30f;
    #pragma unroll
    for (int k = 0; k < 16; ++k) {
      vv[k] = lB[c * (256 * G_) + (a + 16 * k) * G_ + g];
      mx = fmaxf(mx, vv[k]);
    }
    mx = grpmax16(mx);
    float ssum = 0.f;
    #pragma unroll
    for (int k = 0; k < 16; ++k) { vv[k] = __expf(vv[k] - mx); ssum += vv[k]; }
    ssum = grpsum16(ssum);
    float is = RCP(ssum);
    #pragma unroll
    for (int k = 0; k < 16; ++k) sB[(a + 16 * k) * 17 + c] = vv[k] * is;
  }
  __syncthreads();

  // ---- per-lane rotated weight vectors: w[r] = A[a][(a-r)&15][l] * SP[l] ----
  f16v w0, w1;
  #pragma unroll
  for (int r = 0; r < 16; ++r) {
    int b = (a - r) & 15;
    w0[r] = sA[b * 16 + a] * SP0;
    w1[r] = sA[(16 + b) * 16 + a] * SP1;
  }
  const float pi0 = sPi[a], pi1 = sPi[16 + a];
  const float* sBa = sB + a;

  // ---- hoist all 32 leaf gathers: pipelined bpermute+LDS reads up front ----
  f16v lfx, lfy;
  #pragma unroll
  for (int j = 0; j < 16; ++j) {
    int xp = __shfl(leafp, j, 16);
    float pi = (j & 1) ? pi1 : pi0;
    lfx[j] = pi * sBa[xp & 0xFFFF];
    lfy[j] = pi * sBa[((unsigned)xp) >> 16];
  }

  float2 ll = {0.f, 0.f};
  float2 rraw, rrcp, rnu;
  evalN<0, 0>(sBa, w0, w1, lfx, lfy, intp, ll, rraw, rrcp, rnu);
  ll.x += __log2f(rnu.x);
  ll.y += __log2f(rnu.y);
  roots[grp * 17 + a]        = rraw.x * rrcp.x;
  roots[(grp + 16) * 17 + a] = rraw.y * rrcp.y;
  __syncthreads();

  // ---- top 31 nodes (levels 4..0) ----
  float llt = 0.f;
  topStep(roots, topA, 16, 4, sB, w0, w1, a, grp, topx, llt);
  topStep(topA, topB, 8, 3, sB, w0, w1, a, grp, topx, llt);
  topStep(topB, topA, 4, 2, sB, w0, w1, a, grp, topx, llt);
  topStep(topA, topB, 2, 1, sB, w0, w1, a, grp, topx, llt);
  topStep(topB, nullptr, 1, 0, sB, w0, w1, a, grp, topx, llt);

  // ---- block reduce; scale: x16 lane duplication and log2 -> ln ----
  float v = ll.x + ll.y + llt;
  #pragma unroll
  for (int off = 32; off > 0; off >>= 1) v += __shfl_down(v, off, 64);
  if ((tid & 63) == 0) red[tid >> 6] = v;
  __syncthreads();
  if (tid == 0)
    out[bid] = (red[0] + red[1] + red[2] + red[3]) * (0.6931471805599453f / 16.f);
}

extern "C" void kernel_launch(void* const* d_in, const int* in_sizes, int n_in,
                              void* d_out, int out_size, void* d_ws, size_t ws_size,
                              hipStream_t stream) {
  const float* lA  = (const float*)d_in[0];
  const float* lB  = (const float*)d_in[1];
  const float* lPi = (const float*)d_in[2];
  const float* lSP = (const float*)d_in[3];
  const int*   x   = (const int*)d_in[4];
  float* out = (float*)d_out;
  htmm_fwd_kernel<<<dim3(NT_ * G_), dim3(256), 0, stream>>>(lA, lB, lPi, lSP, x, out);
}

// Round 8
// 26.492 us; speedup vs baseline: 1.4138x; 1.0049x over previous
//
#include <hip/hip_runtime.h>

// Bottom-up HTMM forward. One block per (tree, generator); 16 groups of 16
// lanes. Group grp evaluates the SIBLING subtree pair {2grp, 2grp+1} as one
// float2 register chain and finishes with their level-4 parent in-chain
// (no LDS round-trip). 16x16 matvec via hand-fused v_fmac_f32_dpp (row_ror);
// 16-lane reductions via v_add_f32_dpp. Leaf gathers + all global x loads
// hoisted; nus logged pairwise/triple in log2, scaled once at the end.
// Top phase: only 15 nodes (levels 3..0), 4 barriers.
#define G_   8
#define NT_  128
#define NPT_ 1023

typedef float f16v __attribute__((ext_vector_type(16)));
#define RCP(x) __builtin_amdgcn_rcpf(x)

// lane i receives v[(i - R) & 15] within its 16-lane row (row_ror)
template<int R>
__device__ __forceinline__ float rotr16(float v) {
  return __int_as_float(__builtin_amdgcn_update_dpp(
      0, __float_as_int(v), 0x120 | R, 0xF, 0xF, true));
}
// builtin-path reduces (compiler handles DPP hazards) — prologue/parent/top
__device__ __forceinline__ float grpsum16(float v) {
  v += rotr16<8>(v); v += rotr16<4>(v); v += rotr16<2>(v); v += rotr16<1>(v);
  return v;
}
__device__ __forceinline__ float grpmax16(float v) {
  v = fmaxf(v, rotr16<8>(v)); v = fmaxf(v, rotr16<4>(v));
  v = fmaxf(v, rotr16<2>(v)); v = fmaxf(v, rotr16<1>(v));
  return v;
}

// ---- hot path: 4 dots (L/R children x float2) with fused v_fmac_f32_dpp.
// Round-robin over 4 accumulators: self-dep distance 4 >= FMA latency; DPP
// source operands written well before (s_nop 1 guards block entry).
#define FMAC4_R(R) \
  asm("v_fmac_f32_dpp %0, %4, %8 row_ror:" #R " row_mask:0xf bank_mask:0xf\n\t" \
      "v_fmac_f32_dpp %1, %5, %8 row_ror:" #R " row_mask:0xf bank_mask:0xf\n\t" \
      "v_fmac_f32_dpp %2, %6, %9 row_ror:" #R " row_mask:0xf bank_mask:0xf\n\t" \
      "v_fmac_f32_dpp %3, %7, %9 row_ror:" #R " row_mask:0xf bank_mask:0xf"     \
      : "+v"(aLx), "+v"(aLy), "+v"(aRx), "+v"(aRy)                              \
      : "v"(vLx), "v"(vLy), "v"(vRx), "v"(vRy), "v"(w0[R]), "v"(w1[R]))
#define FMAC4_FIRST(R) \
  asm("s_nop 1\n\t"                                                             \
      "v_fmac_f32_dpp %0, %4, %8 row_ror:" #R " row_mask:0xf bank_mask:0xf\n\t" \
      "v_fmac_f32_dpp %1, %5, %8 row_ror:" #R " row_mask:0xf bank_mask:0xf\n\t" \
      "v_fmac_f32_dpp %2, %6, %9 row_ror:" #R " row_mask:0xf bank_mask:0xf\n\t" \
      "v_fmac_f32_dpp %3, %7, %9 row_ror:" #R " row_mask:0xf bank_mask:0xf"     \
      : "+v"(aLx), "+v"(aLy), "+v"(aRx), "+v"(aRy)                              \
      : "v"(vLx), "v"(vLy), "v"(vRx), "v"(vRy), "v"(w0[R]), "v"(w1[R]))

__device__ __forceinline__ void dot4(float vLx, float vLy, float vRx, float vRy,
                                     const f16v& w0, const f16v& w1,
                                     float& oLx, float& oLy, float& oRx, float& oRy) {
  float aLx = vLx * w0[0];
  float aLy = vLy * w0[0];
  float aRx = vRx * w1[0];
  float aRy = vRy * w1[0];
  FMAC4_FIRST(1);
  FMAC4_R(2);  FMAC4_R(3);  FMAC4_R(4);  FMAC4_R(5);
  FMAC4_R(6);  FMAC4_R(7);  FMAC4_R(8);  FMAC4_R(9);
  FMAC4_R(10); FMAC4_R(11); FMAC4_R(12); FMAC4_R(13);
  FMAC4_R(14); FMAC4_R(15);
  oLx = aLx; oLy = aLy; oRx = aRx; oRy = aRy;
}

// ---- 2 dots fused (parent node + top phase): self-dep distance 2 = FMA lat
#define FMAC2_R(R) \
  asm("v_fmac_f32_dpp %0, %2, %4 row_ror:" #R " row_mask:0xf bank_mask:0xf\n\t" \
      "v_fmac_f32_dpp %1, %3, %5 row_ror:" #R " row_mask:0xf bank_mask:0xf"     \
      : "+v"(aL), "+v"(aR)                                                      \
      : "v"(vL), "v"(vR), "v"(w0[R]), "v"(w1[R]))
#define FMAC2_FIRST(R) \
  asm("s_nop 1\n\t"                                                             \
      "v_fmac_f32_dpp %0, %2, %4 row_ror:" #R " row_mask:0xf bank_mask:0xf\n\t" \
      "v_fmac_f32_dpp %1, %3, %5 row_ror:" #R " row_mask:0xf bank_mask:0xf"     \
      : "+v"(aL), "+v"(aR)                                                      \
      : "v"(vL), "v"(vR), "v"(w0[R]), "v"(w1[R]))

__device__ __forceinline__ void dot2f(float vL, float vR,
                                      const f16v& w0, const f16v& w1,
                                      float& oL, float& oR) {
  float aL = vL * w0[0];
  float aR = vR * w1[0];
  FMAC2_FIRST(1);
  FMAC2_R(2);  FMAC2_R(3);  FMAC2_R(4);  FMAC2_R(5);
  FMAC2_R(6);  FMAC2_R(7);  FMAC2_R(8);  FMAC2_R(9);
  FMAC2_R(10); FMAC2_R(11); FMAC2_R(12); FMAC2_R(13);
  FMAC2_R(14); FMAC2_R(15);
  oL = aL; oR = aR;
}

// dual 16-lane sum via v_add_f32_dpp; s_nops cover the same-reg
// VALU-write -> DPP-read hazard the compiler can't see.
__device__ __forceinline__ void grpsum2(float rx, float ry, float& nux, float& nuy) {
  asm("s_nop 1\n\t"
      "v_add_f32_dpp %0, %2, %2 row_ror:8 row_mask:0xf bank_mask:0xf\n\t"
      "v_add_f32_dpp %1, %3, %3 row_ror:8 row_mask:0xf bank_mask:0xf\n\t"
      "s_nop 0\n\t"
      "v_add_f32_dpp %0, %0, %0 row_ror:4 row_mask:0xf bank_mask:0xf\n\t"
      "v_add_f32_dpp %1, %1, %1 row_ror:4 row_mask:0xf bank_mask:0xf\n\t"
      "s_nop 0\n\t"
      "v_add_f32_dpp %0, %0, %0 row_ror:2 row_mask:0xf bank_mask:0xf\n\t"
      "v_add_f32_dpp %1, %1, %1 row_ror:2 row_mask:0xf bank_mask:0xf\n\t"
      "s_nop 0\n\t"
      "v_add_f32_dpp %0, %0, %0 row_ror:1 row_mask:0xf bank_mask:0xf\n\t"
      "v_add_f32_dpp %1, %1, %1 row_ror:1 row_mask:0xf bank_mask:0xf"
      : "=&v"(nux), "=&v"(nuy)
      : "v"(rx), "v"(ry));
}

// quad 16-lane sum: 4 interleaved DPP chains, round-robin distance 4 -> no
// nops needed (inputs are long-lived leaf registers).
__device__ __forceinline__ void grpsum4(float r0, float r1, float r2, float r3,
                                        float& n0, float& n1, float& n2, float& n3) {
  asm("v_add_f32_dpp %0, %4, %4 row_ror:8 row_mask:0xf bank_mask:0xf\n\t"
      "v_add_f32_dpp %1, %5, %5 row_ror:8 row_mask:0xf bank_mask:0xf\n\t"
      "v_add_f32_dpp %2, %6, %6 row_ror:8 row_mask:0xf bank_mask:0xf\n\t"
      "v_add_f32_dpp %3, %7, %7 row_ror:8 row_mask:0xf bank_mask:0xf\n\t"
      "v_add_f32_dpp %0, %0, %0 row_ror:4 row_mask:0xf bank_mask:0xf\n\t"
      "v_add_f32_dpp %1, %1, %1 row_ror:4 row_mask:0xf bank_mask:0xf\n\t"
      "v_add_f32_dpp %2, %2, %2 row_ror:4 row_mask:0xf bank_mask:0xf\n\t"
      "v_add_f32_dpp %3, %3, %3 row_ror:4 row_mask:0xf bank_mask:0xf\n\t"
      "v_add_f32_dpp %0, %0, %0 row_ror:2 row_mask:0xf bank_mask:0xf\n\t"
      "v_add_f32_dpp %1, %1, %1 row_ror:2 row_mask:0xf bank_mask:0xf\n\t"
      "v_add_f32_dpp %2, %2, %2 row_ror:2 row_mask:0xf bank_mask:0xf\n\t"
      "v_add_f32_dpp %3, %3, %3 row_ror:2 row_mask:0xf bank_mask:0xf\n\t"
      "v_add_f32_dpp %0, %0, %0 row_ror:1 row_mask:0xf bank_mask:0xf\n\t"
      "v_add_f32_dpp %1, %1, %1 row_ror:1 row_mask:0xf bank_mask:0xf\n\t"
      "v_add_f32_dpp %2, %2, %2 row_ror:1 row_mask:0xf bank_mask:0xf\n\t"
      "v_add_f32_dpp %3, %3, %3 row_ror:1 row_mask:0xf bank_mask:0xf"
      : "=&v"(n0), "=&v"(n1), "=&v"(n2), "=&v"(n3)
      : "v"(r0), "v"(r1), "v"(r2), "v"(r3));
}

// Post-order evaluation of two sibling depth-5 subtrees (float2 .x = left
// subtree 2*grp, .y = right subtree 2*grp+1). DELTA 0..3; leaves pre-gathered.
// Each node RETURNS nu (unlogged); parent logs log2(nuL*nuR).
template<int DELTA, int J>
__device__ __forceinline__ void evalN(const float* __restrict__ sBa,
                                      const f16v& w0, const f16v& w1,
                                      const f16v& lfx, const f16v& lfy,
                                      int intp,
                                      float2& ll, float2& raw, float2& rcpv,
                                      float2& nuOut) {
  // prefetch this node's B-gather before descending (hides LDS latency)
  int xp = __shfl(intp, (1 << DELTA) - 1 + J, 16);
  float bvA = sBa[xp & 0xFFFF];
  float bvB = sBa[((unsigned)xp) >> 16];
  float2 rawL, rcpL, rawR, rcpR;
  if constexpr (DELTA == 3) {
    // leaves 2J, 2J+1 from hoisted registers; one 4-wide reduce, paired logs
    float rLx = lfx[2 * J],     rLy = lfy[2 * J];
    float rRx = lfx[2 * J + 1], rRy = lfy[2 * J + 1];
    float nLx, nLy, nRx, nRy;
    grpsum4(rLx, rLy, rRx, rRy, nLx, nLy, nRx, nRy);
    ll.x += __log2f(nLx * nRx);
    ll.y += __log2f(nLy * nRy);
    rawL.x = rLx; rawL.y = rLy; rawR.x = rRx; rawR.y = rRy;
    rcpL.x = RCP(nLx); rcpL.y = RCP(nLy);
    rcpR.x = RCP(nRx); rcpR.y = RCP(nRy);
  } else {
    float2 nuL, nuR;
    evalN<DELTA + 1, 2 * J>(sBa, w0, w1, lfx, lfy, intp, ll, rawL, rcpL, nuL);
    evalN<DELTA + 1, 2 * J + 1>(sBa, w0, w1, lfx, lfy, intp, ll, rawR, rcpR, nuR);
    ll.x += __log2f(nuL.x * nuR.x);
    ll.y += __log2f(nuL.y * nuR.y);
  }
  float dLx, dLy, dRx, dRy;
  dot4(rawL.x, rawL.y, rawR.x, rawR.y, w0, w1, dLx, dLy, dRx, dRy);
  float tx = fmaf(dLx, rcpL.x, dRx * rcpR.x);
  float ty = fmaf(dLy, rcpL.y, dRy * rcpR.y);
  raw.x = tx * bvA;
  raw.y = ty * bvB;
  float nux, nuy;
  grpsum2(raw.x, raw.y, nux, nuy);
  nuOut.x = nux; nuOut.y = nuy;
  rcpv.x = RCP(nux);
  rcpv.y = RCP(nuy);
}

template<bool SYNC>
__device__ __forceinline__ void topStep(const float* __restrict__ child,
                                        float* parent, int U, int lvl,
                                        const float* __restrict__ sB,
                                        const f16v& w0, const f16v& w1,
                                        int a, int grp, int topx, float& ll) {
  int j = (grp < U) ? grp : 0;            // clamp: keep full-wave EXEC for DPP
  int node = (1 << lvl) - 1 + j;
  int xi = __shfl(topx, node, 64);
  float bval = sB[xi * 17 + a];
  float vL = child[(2 * j) * 17 + a];
  float vR = child[(2 * j + 1) * 17 + a];
  float dL, dR;
  dot2f(vL, vR, w0, w1, dL, dR);
  float bu = (dL + dR) * bval;
  float nu = grpsum16(bu);
  if (grp < U) {
    ll += __log2f(nu);
    if (parent) parent[grp * 17 + a] = bu * RCP(nu);
  }
  if constexpr (SYNC) __syncthreads();
}

__global__ __launch_bounds__(256, 4) void htmm_fwd_kernel(
    const float* __restrict__ lA,   // (16,16,2,8)
    const float* __restrict__ lB,   // (16,256,8)
    const float* __restrict__ lPi,  // (16,2,8)
    const float* __restrict__ lSP,  // (2,8)
    const int*   __restrict__ x,    // (128*1023,)
    float*       __restrict__ out)  // (128,8)
{
  __shared__ float sB[256 * 17];    // normalized B, [m][c], stride 17
  __shared__ float sA[2 * 16 * 16]; // normalized A, [l][b][a]
  __shared__ float sPi[32];         // [l][c]
  __shared__ float roots[16 * 17];  // level-4 beliefs (one per group)
  __shared__ float topA[8 * 17];
  __shared__ float topB[4 * 17];
  __shared__ float red[4];

  const int tid = threadIdx.x;
  const int bid = blockIdx.x;       // tree*8 + g
  const int T   = bid >> 3;
  const int g   = bid & 7;
  const int a   = tid & 15;
  const int grp = tid >> 4;
  const long base = (long)T * NPT_;
  const int sx = 2 * grp;           // left sibling subtree
  const int sy = 2 * grp + 1;       // right sibling subtree

  // ---- ALL global x loads first: latency hides under the softmax prologue --
  int lxA = x[base + 511 + 16 * sx + a] * 17;
  int lxB = x[base + 511 + 16 * sy + a] * 17;
  int leafp = lxA | (lxB << 16);
  int dpl = 31 - __clz(a + 1);
  int iA = (a < 15) ? x[base + ((31 + sx) << dpl) + a] * 17 : 0;
  int iB = (a < 15) ? x[base + ((31 + sy) << dpl) + a] * 17 : 0;
  int intp = iA | (iB << 16);
  int xpar = x[base + 15 + grp] * 17;                // level-4 parent obs
  int tl = tid & 63;
  int topx = x[base + (tl < 15 ? tl : 0)];           // x[0..14] in wave lanes

  // ---- SP softmax ----
  float s0 = lSP[g], s1 = lSP[G_ + g];
  float sm = fmaxf(s0, s1);
  float e0 = __expf(s0 - sm), e1 = __expf(s1 - sm);
  float inv = RCP(e0 + e1);
  const float SP0 = e0 * inv, SP1 = e1 * inv;

  // ---- A softmax over axis 0 (lanes = a), column b = grp ----
  #pragma unroll
  for (int l = 0; l < 2; ++l) {
    float v = lA[a * 256 + grp * 16 + l * 8 + g];
    float m = grpmax16(v);
    float e = __expf(v - m);
    float s = grpsum16(e);
    sA[(l * 16 + grp) * 16 + a] = e * RCP(s);
  }
  // ---- Pi softmax over axis 0 ----
  if (grp < 2) {
    float v = lPi[a * 16 + grp * 8 + g];
    float m = grpmax16(v);
    float e = __expf(v - m);
    float s = grpsum16(e);
    sPi[grp * 16 + a] = e * RCP(s);
  }
  // ---- B softmax over axis 1 (M): row c = grp, lane a covers m = a+16k ----
  {
    const int c = grp;
    float vv[16];
    float mx = -1e30f;
    #pragma unroll
    for (int k = 0; k < 16; ++k) {
      vv[k] = lB[c * (256 * G_) + (a + 16 * k) * G_ + g];
      mx = fmaxf(mx, vv[k]);
    }
    mx = grpmax16(mx);
    float ssum = 0.f;
    #pragma unroll
    for (int k = 0; k < 16; ++k) { vv[k] = __expf(vv[k] - mx); ssum += vv[k]; }
    ssum = grpsum16(ssum);
    float is = RCP(ssum);
    #pragma unroll
    for (int k = 0; k < 16; ++k) sB[(a + 16 * k) * 17 + c] = vv[k] * is;
  }
  __syncthreads();

  // ---- per-lane rotated weight vectors: w[r] = A[a][(a-r)&15][l] * SP[l] ----
  f16v w0, w1;
  #pragma unroll
  for (int r = 0; r < 16; ++r) {
    int b = (a - r) & 15;
    w0[r] = sA[b * 16 + a] * SP0;
    w1[r] = sA[(16 + b) * 16 + a] * SP1;
  }
  const float pi0 = sPi[a], pi1 = sPi[16 + a];
  const float* sBa = sB + a;

  // ---- hoist all 32 leaf gathers: pipelined bpermute+LDS reads up front ----
  f16v lfx, lfy;
  #pragma unroll
  for (int j = 0; j < 16; ++j) {
    int xp = __shfl(leafp, j, 16);
    float pi = (j & 1) ? pi1 : pi0;
    lfx[j] = pi * sBa[xp & 0xFFFF];
    lfy[j] = pi * sBa[((unsigned)xp) >> 16];
  }

  float2 ll = {0.f, 0.f};
  float2 rraw, rrcp, rnu;
  evalN<0, 0>(sBa, w0, w1, lfx, lfy, intp, ll, rraw, rrcp, rnu);

  // ---- in-chain level-4 parent: left child = subtree sx, right = sy ----
  {
    float bvP = sBa[xpar];
    float dL, dR;
    dot2f(rraw.x, rraw.y, w0, w1, dL, dR);
    float t = fmaf(dL, rrcp.x, dR * rrcp.y);
    float praw = t * bvP;
    float nup = grpsum16(praw);
    ll.x += __log2f(rnu.x * rnu.y * nup);   // triple-paired log, >= ~1e-18
    roots[grp * 17 + a] = praw * RCP(nup);
  }
  __syncthreads();

  // ---- top 15 nodes (levels 3..0) ----
  float llt = 0.f;
  topStep<true>(roots, topA, 8, 3, sB, w0, w1, a, grp, topx, llt);
  topStep<true>(topA, topB, 4, 2, sB, w0, w1, a, grp, topx, llt);
  topStep<true>(topB, topA, 2, 1, sB, w0, w1, a, grp, topx, llt);
  topStep<false>(topA, nullptr, 1, 0, sB, w0, w1, a, grp, topx, llt);

  // ---- block reduce; scale: x16 lane duplication and log2 -> ln ----
  float v = ll.x + ll.y + llt;
  #pragma unroll
  for (int off = 32; off > 0; off >>= 1) v += __shfl_down(v, off, 64);
  if ((tid & 63) == 0) red[tid >> 6] = v;
  __syncthreads();
  if (tid == 0)
    out[bid] = (red[0] + red[1] + red[2] + red[3]) * (0.6931471805599453f / 16.f);
}

extern "C" void kernel_launch(void* const* d_in, const int* in_sizes, int n_in,
                              void* d_out, int out_size, void* d_ws, size_t ws_size,
                              hipStream_t stream) {
  const float* lA  = (const float*)d_in[0];
  const float* lB  = (const float*)d_in[1];
  const float* lPi = (const float*)d_in[2];
  const float* lSP = (const float*)d_in[3];
  const int*   x   = (const int*)d_in[4];
  float* out = (float*)d_out;
  htmm_fwd_kernel<<<dim3(NT_ * G_), dim3(256), 0, stream>>>(lA, lB, lPi, lSP, x, out);
}